// Round 8
// baseline (290.266 us; speedup 1.0000x reference)
//
#include <hip/hip_runtime.h>

typedef unsigned short u16;
typedef unsigned int u32;
typedef __attribute__((ext_vector_type(8))) short sh8;
typedef __attribute__((ext_vector_type(4))) float f32x4;
typedef __attribute__((ext_vector_type(4))) unsigned short us4;

__device__ __forceinline__ float bf2f(u16 u) {
  union { u32 i; float f; } x; x.i = ((u32)u) << 16; return x.f;
}
__device__ __forceinline__ u16 f2bf(float f) {
  union { float f; u32 i; } x; x.f = f;
  u32 u = x.i;
  u32 r = (u + 0x7FFFu + ((u >> 16) & 1u)) >> 16;
  return (u16)r;
}

__device__ __forceinline__ sh8 load8f_nt(const float* p, size_t off) {
  const f32x4* f = (const f32x4*)(p + off);
  f32x4 x = __builtin_nontemporal_load(f);
  f32x4 y = __builtin_nontemporal_load(f + 1);
  sh8 r;
  r[0] = (short)f2bf(x[0]); r[1] = (short)f2bf(x[1]);
  r[2] = (short)f2bf(x[2]); r[3] = (short)f2bf(x[3]);
  r[4] = (short)f2bf(y[0]); r[5] = (short)f2bf(y[1]);
  r[6] = (short)f2bf(y[2]); r[7] = (short)f2bf(y[3]);
  return r;
}

// ---------------- prep + degree count (R7: fused; cnt pre-zeroed) -----------
__global__ void k_prep(const float* __restrict__ Ws, const float* __restrict__ Wn,
                       const float* __restrict__ Wm, const float* __restrict__ Wg,
                       const float* __restrict__ b_sage, const float* __restrict__ bg,
                       const float* __restrict__ bm, const float* __restrict__ ln_g,
                       const float* __restrict__ ln_b, const int* __restrict__ dst,
                       u16* __restrict__ WmT, u16* __restrict__ WsT, u16* __restrict__ WnT,
                       u16* __restrict__ WsgT, u16* __restrict__ WngT, u16* __restrict__ WgBT,
                       float* __restrict__ bm_f, float* __restrict__ lng_f,
                       float* __restrict__ lnb_f, float* __restrict__ bsage_f,
                       float* __restrict__ bsg, int* __restrict__ cnt, int E) {
  int idx = blockIdx.x * blockDim.x + threadIdx.x;
  int stride = gridDim.x * blockDim.x;
  for (int i = idx; i < 32768; i += stride) {
    int n = i >> 8, k = i & 255;
    WmT[n * 256 + k] = f2bf(Wm[k * 128 + n]);
  }
  for (int i = idx; i < 16384; i += stride) {
    int n = i >> 7, k = i & 127;
    WsT[i] = f2bf(Ws[k * 128 + n]);
    WnT[i] = f2bf(Wn[k * 128 + n]);
    WgBT[i] = f2bf(Wg[(128 + k) * 128 + n]);
  }
  for (int i = idx; i < 16384; i += stride) {
    int c = i >> 7, k = i & 127;
    float s1 = 0.f, s2 = 0.f;
    for (int j = 0; j < 128; ++j) {
      float wg = Wg[j * 128 + c];
      s1 += Ws[k * 128 + j] * wg;
      s2 += Wn[k * 128 + j] * wg;
    }
    WsgT[c * 128 + k] = f2bf(s1);
    WngT[c * 128 + k] = f2bf(s2);
  }
  for (int i = idx; i < 128; i += stride) {
    bm_f[i] = bm[i];
    lng_f[i] = ln_g[i];
    lnb_f[i] = ln_b[i];
    bsage_f[i] = b_sage[i];
    float s = bg[i];
    for (int j = 0; j < 128; ++j) s += b_sage[j] * Wg[j * 128 + i];
    bsg[i] = s;
  }
  for (int e = idx; e < E; e += stride) atomicAdd(&cnt[dst[e]], 1);
}

// ---------------- CSR scan: single kernel (R8: scan1+scan23 merged) ---------
// Block c brute-force sums cnt[0..c*256) for its prefix base (~19MB L2 total).
__global__ void k_scan(const int* __restrict__ cnt, int* __restrict__ rowptr,
                       int* __restrict__ cursor, int N) {
  __shared__ int ws2[4];
  __shared__ int s[256];
  int t = threadIdx.x;
  int c = blockIdx.x;
  int lim = c * 256;
  int base = 0;
  for (int j = t; j < lim; j += 256) base += cnt[j];
#pragma unroll
  for (int m = 1; m < 64; m <<= 1) base += __shfl_xor(base, m, 64);
  if ((t & 63) == 0) ws2[t >> 6] = base;
  __syncthreads();
  base = ws2[0] + ws2[1] + ws2[2] + ws2[3];
  int i = lim + t;
  int v = (i < N) ? cnt[i] : 0;
  s[t] = v;
  __syncthreads();
  for (int off = 1; off < 256; off <<= 1) {
    int x = (t >= off) ? s[t - off] : 0;
    __syncthreads();
    s[t] += x;
    __syncthreads();
  }
  int excl = base + s[t] - v;
  if (i < N) {
    rowptr[i] = excl;
    cursor[i] = excl;
    if (i == N - 1) rowptr[N] = excl + v;
  }
}

__global__ void k_perm(const int* __restrict__ src, const int* __restrict__ dst,
                       int* __restrict__ cursor, int* __restrict__ src_sorted, int E) {
  int e = blockIdx.x * blockDim.x + threadIdx.x;
  if (e < E) {
    int p = atomicAdd(&cursor[dst[e]], 1);
    src_sorted[p] = src[e];
  }
}

// ---------------- node MLP: M = relu(LN(concat(h,ctx)@Wm + bm)) -------------
// R3 structure (verified): weights in VGPRs (A), node tile in 8KB LDS (B).
__global__ __launch_bounds__(512) void k_node(
    const float* __restrict__ h, const float* __restrict__ ctx,
    const u16* __restrict__ WmT, const float* __restrict__ bm_f,
    const float* __restrict__ lng_f, const float* __restrict__ lnb_f,
    u16* __restrict__ hm, int N) {
  __shared__ u16 atile[16 * 256];
  __shared__ u16 mtile[16 * 128];
  __shared__ float scr[8 * 16 * 2];
  int tid = threadIdx.x;
  int lane = tid & 63;
  int wave = tid >> 6;
  int col16 = lane & 15;
  int quad = lane >> 4;

  sh8 areg[8];
#pragma unroll
  for (int ks = 0; ks < 8; ++ks)
    areg[ks] = *(const sh8*)&WmT[(size_t)(wave * 16 + col16) * 256 + ks * 32 + quad * 8];

  float bmv[4], gv[4], bv[4];
#pragma unroll
  for (int r = 0; r < 4; ++r) {
    int c = wave * 16 + quad * 4 + r;
    bmv[r] = bm_f[c]; gv[r] = lng_f[c]; bv[r] = lnb_f[c];
  }

  int srow = tid >> 5;
  int c8 = tid & 31;
  int TT = (N + 15) >> 4;
  for (int tile = blockIdx.x; tile < TT; tile += gridDim.x) {
    int n0 = tile * 16;
    {
      int node = min(n0 + srow, N - 1);
      sh8 a = (c8 < 16) ? load8f_nt(h, (size_t)node * 128 + c8 * 8)
                        : load8f_nt(ctx, (size_t)node * 128 + (c8 - 16) * 8);
      *(sh8*)&atile[srow * 256 + ((c8 ^ (srow & 7)) << 3)] = a;
      if (c8 < 16 && n0 + srow < N)
        __builtin_nontemporal_store(a, (sh8*)&hm[(size_t)(n0 + srow) * 256 + c8 * 8]);
    }
    __syncthreads();
    f32x4 acc = (f32x4)0.0f;
#pragma unroll
    for (int ks = 0; ks < 8; ++ks) {
      int chunk = ks * 4 + quad;
      sh8 b = *(const sh8*)&atile[col16 * 256 + ((chunk ^ (col16 & 7)) << 3)];
      acc = __builtin_amdgcn_mfma_f32_16x16x32_bf16(areg[ks], b, acc, 0, 0, 0);
    }
    float v[4], s1 = 0.f, s2 = 0.f;
#pragma unroll
    for (int r = 0; r < 4; ++r) {
      v[r] = acc[r] + bmv[r];
      s1 += v[r]; s2 += v[r] * v[r];
    }
    s1 += __shfl_xor(s1, 16, 64); s2 += __shfl_xor(s2, 16, 64);
    s1 += __shfl_xor(s1, 32, 64); s2 += __shfl_xor(s2, 32, 64);
    if (lane < 16) {
      scr[(wave * 16 + lane) * 2 + 0] = s1;
      scr[(wave * 16 + lane) * 2 + 1] = s2;
    }
    __syncthreads();
    float t1 = 0.f, t2 = 0.f;
#pragma unroll
    for (int w2 = 0; w2 < 8; ++w2) {
      t1 += scr[(w2 * 16 + col16) * 2 + 0];
      t2 += scr[(w2 * 16 + col16) * 2 + 1];
    }
    float mu = t1 * (1.f / 128.f);
    float var = t2 * (1.f / 128.f) - mu * mu;
    float rstd = rsqrtf(fmaxf(var, 0.f) + 1e-5f);
    us4 pk;
#pragma unroll
    for (int r = 0; r < 4; ++r) {
      float x = (v[r] - mu) * rstd * gv[r] + bv[r];
      x = x > 0.f ? x : 0.f;
      pk[r] = f2bf(x);
    }
    *(us4*)&mtile[col16 * 128 + wave * 16 + quad * 4] = pk;
    __syncthreads();
    if (tid < 256) {
      int row = tid >> 4, ch = tid & 15;
      if (n0 + row < N) {
        sh8 mv = *(const sh8*)&mtile[row * 128 + ch * 8];
        __builtin_nontemporal_store(mv, (sh8*)&hm[(size_t)(n0 + row) * 256 + 128 + ch * 8]);
      }
    }
  }
}

// ---------------- fused aggregation + output GEMMs + gate + blend (R8) ------
// Supertile = 64 nodes per block. Phase A: gather-mean of neighbor hm rows
// into LDS (nm/cagg never hit HBM); also stage own hm h-half. Phase B: 8
// waves each own 16 output cols with all 5 B-matrices in VGPRs (20x sh8);
// 4 sub-tiles x 20 MFMA; epilogue blends with cagg from LDS. Work-stealing
// via atomic ctr for block balance.
__global__ __launch_bounds__(512, 4) void k_aggout(
    const u16* __restrict__ hm, const int* __restrict__ rowptr,
    const int* __restrict__ src_sorted,
    const u16* __restrict__ WsT, const u16* __restrict__ WnT,
    const u16* __restrict__ WsgT, const u16* __restrict__ WngT,
    const u16* __restrict__ WgBT,
    const float* __restrict__ bsage_f, const float* __restrict__ bsg,
    int* __restrict__ ctr, float* __restrict__ out, int N) {
  __shared__ u16 hmlds[64 * 128];    // 16 KB own-row h-half (swizzled)
  __shared__ u16 nmlds[64 * 128];    // 16 KB gathered h-mean (swizzled)
  __shared__ u16 cagglds[64 * 128];  // 16 KB gathered M-mean (swizzled)
  __shared__ int st_s;
  int tid = threadIdx.x;
  int lane = tid & 63;
  int wave = tid >> 6;
  int col16 = lane & 15, quad = lane >> 4;
  int half = lane >> 5, cl = lane & 31;

  // B fragments: wave owns output cols wave*16 .. wave*16+15.
  sh8 bW[5][4];
  {
    const u16* matp[5] = {WsT, WnT, WsgT, WngT, WgBT};
#pragma unroll
    for (int m = 0; m < 5; ++m)
#pragma unroll
      for (int ks = 0; ks < 4; ++ks)
        bW[m][ks] = *(const sh8*)&matp[m][(size_t)(wave * 16 + col16) * 128 +
                                          (ks * 4 + quad) * 8];
  }
  float bsv = bsage_f[wave * 16 + col16];
  float bgv = bsg[wave * 16 + col16];

  int NT = (N + 63) >> 6;
  for (;;) {
    if (tid == 0) st_s = atomicAdd(ctr, 1);
    __syncthreads();
    int st = st_s;
    if (st >= NT) break;
    int n0 = st << 6;
    // ---- stage own hm h-half: 64 rows x 16 chunks, 2 chunks/thread ----
    {
      int row = tid >> 3;
      int ch = tid & 7;
      int node = min(n0 + row, N - 1);
#pragma unroll
      for (int j = 0; j < 2; ++j) {
        int chunk = ch + j * 8;
        sh8 v = *(const sh8*)&hm[(size_t)node * 256 + chunk * 8];
        *(sh8*)&hmlds[row * 128 + ((chunk ^ (row & 7)) << 3)] = v;
      }
    }
    // ---- gather: wave w handles nodes n0 + w*8 + 0..7 (R5 pair scheme) ----
    for (int j = 0; j < 8; ++j) {
      int n = n0 + wave * 8 + j;
      if (n >= N) break;
      int b = rowptr[n], e = rowptr[n + 1];
      float a0 = 0.f, a1 = 0.f, a2 = 0.f, a3 = 0.f;
      float a4 = 0.f, a5 = 0.f, a6 = 0.f, a7 = 0.f;
      int i = b;
      for (; i + 4 <= e; i += 4) {
        int s0 = src_sorted[i + half];
        int s1 = src_sorted[i + 2 + half];
        sh8 v0 = *(const sh8*)(hm + (size_t)s0 * 256 + (cl << 3));
        sh8 v1 = *(const sh8*)(hm + (size_t)s1 * 256 + (cl << 3));
        a0 += bf2f((u16)v0[0]) + bf2f((u16)v1[0]);
        a1 += bf2f((u16)v0[1]) + bf2f((u16)v1[1]);
        a2 += bf2f((u16)v0[2]) + bf2f((u16)v1[2]);
        a3 += bf2f((u16)v0[3]) + bf2f((u16)v1[3]);
        a4 += bf2f((u16)v0[4]) + bf2f((u16)v1[4]);
        a5 += bf2f((u16)v0[5]) + bf2f((u16)v1[5]);
        a6 += bf2f((u16)v0[6]) + bf2f((u16)v1[6]);
        a7 += bf2f((u16)v0[7]) + bf2f((u16)v1[7]);
      }
      for (; i + 2 <= e; i += 2) {
        int s0 = src_sorted[i + half];
        sh8 v0 = *(const sh8*)(hm + (size_t)s0 * 256 + (cl << 3));
        a0 += bf2f((u16)v0[0]); a1 += bf2f((u16)v0[1]);
        a2 += bf2f((u16)v0[2]); a3 += bf2f((u16)v0[3]);
        a4 += bf2f((u16)v0[4]); a5 += bf2f((u16)v0[5]);
        a6 += bf2f((u16)v0[6]); a7 += bf2f((u16)v0[7]);
      }
      if (i < e && half == 0) {
        int s0 = src_sorted[i];
        sh8 v0 = *(const sh8*)(hm + (size_t)s0 * 256 + (cl << 3));
        a0 += bf2f((u16)v0[0]); a1 += bf2f((u16)v0[1]);
        a2 += bf2f((u16)v0[2]); a3 += bf2f((u16)v0[3]);
        a4 += bf2f((u16)v0[4]); a5 += bf2f((u16)v0[5]);
        a6 += bf2f((u16)v0[6]); a7 += bf2f((u16)v0[7]);
      }
      a0 += __shfl_xor(a0, 32, 64); a1 += __shfl_xor(a1, 32, 64);
      a2 += __shfl_xor(a2, 32, 64); a3 += __shfl_xor(a3, 32, 64);
      a4 += __shfl_xor(a4, 32, 64); a5 += __shfl_xor(a5, 32, 64);
      a6 += __shfl_xor(a6, 32, 64); a7 += __shfl_xor(a7, 32, 64);
      if (half == 0) {
        float inv = (e > b) ? 1.f / (float)(e - b) : 0.f;
        sh8 p;
        p[0] = (short)f2bf(a0 * inv); p[1] = (short)f2bf(a1 * inv);
        p[2] = (short)f2bf(a2 * inv); p[3] = (short)f2bf(a3 * inv);
        p[4] = (short)f2bf(a4 * inv); p[5] = (short)f2bf(a5 * inv);
        p[6] = (short)f2bf(a6 * inv); p[7] = (short)f2bf(a7 * inv);
        int row = n - n0;
        if (cl < 16)
          *(sh8*)&nmlds[row * 128 + ((cl ^ (row & 7)) << 3)] = p;
        else
          *(sh8*)&cagglds[row * 128 + (((cl - 16) ^ (row & 7)) << 3)] = p;
      }
    }
    __syncthreads();
    // ---- GEMM: 4 sub-tiles of 16 rows ----
#pragma unroll 1
    for (int t4 = 0; t4 < 4; ++t4) {
      int r0 = t4 * 16;
      int lrow = r0 + col16;  // A-operand row (node) for this lane
      f32x4 as = (f32x4)0.0f, ag = (f32x4)0.0f;
#pragma unroll
      for (int ks = 0; ks < 4; ++ks) {
        int sw = (((ks * 4 + quad) ^ (lrow & 7)) << 3);
        sh8 ah = *(const sh8*)&hmlds[lrow * 128 + sw];
        sh8 am = *(const sh8*)&nmlds[lrow * 128 + sw];
        sh8 ac = *(const sh8*)&cagglds[lrow * 128 + sw];
        as = __builtin_amdgcn_mfma_f32_16x16x32_bf16(ah, bW[0][ks], as, 0, 0, 0);
        as = __builtin_amdgcn_mfma_f32_16x16x32_bf16(am, bW[1][ks], as, 0, 0, 0);
        ag = __builtin_amdgcn_mfma_f32_16x16x32_bf16(ah, bW[2][ks], ag, 0, 0, 0);
        ag = __builtin_amdgcn_mfma_f32_16x16x32_bf16(am, bW[3][ks], ag, 0, 0, 0);
        ag = __builtin_amdgcn_mfma_f32_16x16x32_bf16(ac, bW[4][ks], ag, 0, 0, 0);
      }
      int gc = wave * 16 + col16;
#pragma unroll
      for (int r = 0; r < 4; ++r) {
        int lr = r0 + quad * 4 + r;
        int n = n0 + lr;
        if (n < N) {
          float sv = as[r] + bsv;
          float gl = ag[r] + bgv;
          float g = 1.f / (1.f + __expf(-gl));
          u16 cu = cagglds[lr * 128 + (((gc >> 3) ^ (lr & 7)) << 3) + (gc & 7)];
          float ca = bf2f(cu);
          __builtin_nontemporal_store(g * sv + (1.f - g) * ca,
                                      &out[(size_t)n * 128 + gc]);
        }
      }
    }
    __syncthreads();  // LDS reuse fence before next supertile
  }
}

extern "C" void kernel_launch(void* const* d_in, const int* in_sizes, int n_in,
                              void* d_out, int out_size, void* d_ws, size_t ws_size,
                              hipStream_t stream) {
  const float* h = (const float*)d_in[0];
  const float* ctx = (const float*)d_in[1];
  const int* src = (const int*)d_in[2];
  const int* dst = (const int*)d_in[3];
  const float* Ws = (const float*)d_in[4];
  const float* Wn = (const float*)d_in[5];
  const float* b_sage = (const float*)d_in[6];
  const float* Wm = (const float*)d_in[7];
  const float* bm = (const float*)d_in[8];
  const float* ln_g = (const float*)d_in[9];
  const float* ln_b = (const float*)d_in[10];
  const float* Wg = (const float*)d_in[11];
  const float* bg = (const float*)d_in[12];
  int N = in_sizes[0] / 128;
  int E = in_sizes[2];

  char* w = (char*)d_ws;
  auto carve = [&](size_t bytes) {
    char* p = w;
    w += (bytes + 255) & ~(size_t)255;
    return p;
  };
  int* ctr = (int*)carve(256);              // work-steal counter (zeroed w/ cnt)
  int* cnt = (int*)carve((size_t)N * 4);    // contiguous with ctr
  int* rowptr = (int*)carve((size_t)(N + 1) * 4);
  int* cursor = (int*)carve((size_t)N * 4);
  int* src_sorted = (int*)carve((size_t)E * 4);
  int NB = (N + 255) / 256;
  u16* WmT = (u16*)carve(32768 * 2);
  u16* WsT = (u16*)carve(16384 * 2);
  u16* WnT = (u16*)carve(16384 * 2);
  u16* WsgT = (u16*)carve(16384 * 2);
  u16* WngT = (u16*)carve(16384 * 2);
  u16* WgBT = (u16*)carve(16384 * 2);
  float* bm_f = (float*)carve(128 * 4);
  float* lng_f = (float*)carve(128 * 4);
  float* lnb_f = (float*)carve(128 * 4);
  float* bsage_f = (float*)carve(128 * 4);
  float* bsg = (float*)carve(128 * 4);
  u16* hm = (u16*)carve((size_t)N * 256 * 2);

  // one memset covers ctr + cnt (contiguous carves)
  hipMemsetAsync(ctr, 0, 256 + (((size_t)N * 4 + 255) & ~(size_t)255), stream);
  k_prep<<<256, 256, 0, stream>>>(Ws, Wn, Wm, Wg, b_sage, bg, bm, ln_g, ln_b, dst,
                                  WmT, WsT, WnT, WsgT, WngT, WgBT,
                                  bm_f, lng_f, lnb_f, bsage_f, bsg, cnt, E);
  k_scan<<<NB, 256, 0, stream>>>(cnt, rowptr, cursor, N);
  k_perm<<<(E + 255) / 256, 256, 0, stream>>>(src, dst, cursor, src_sorted, E);
  int TT = (N + 15) / 16;
  int gn = TT < 1024 ? TT : 1024;
  k_node<<<gn, 512, 0, stream>>>(h, ctx, WmT, bm_f, lng_f, lnb_f, hm, N);
  // 512 blocks = 2/CU (48KB LDS, target <=128 VGPR); work-stealing loop.
  k_aggout<<<512, 512, 0, stream>>>(hm, rowptr, src_sorted,
                                    WsT, WnT, WsgT, WngT, WgBT,
                                    bsage_f, bsg, ctr, (float*)d_out, N);
}

// Round 9
// 275.810 us; speedup vs baseline: 1.0524x; 1.0524x over previous
//
#include <hip/hip_runtime.h>

typedef unsigned short u16;
typedef unsigned int u32;
typedef __attribute__((ext_vector_type(8))) short sh8;
typedef __attribute__((ext_vector_type(4))) float f32x4;
typedef __attribute__((ext_vector_type(4))) unsigned short us4;

__device__ __forceinline__ float bf2f(u16 u) {
  union { u32 i; float f; } x; x.i = ((u32)u) << 16; return x.f;
}
__device__ __forceinline__ u16 f2bf(float f) {
  union { float f; u32 i; } x; x.f = f;
  u32 u = x.i;
  u32 r = (u + 0x7FFFu + ((u >> 16) & 1u)) >> 16;
  return (u16)r;
}

__device__ __forceinline__ sh8 load8f_nt(const float* p, size_t off) {
  const f32x4* f = (const f32x4*)(p + off);
  f32x4 x = __builtin_nontemporal_load(f);
  f32x4 y = __builtin_nontemporal_load(f + 1);
  sh8 r;
  r[0] = (short)f2bf(x[0]); r[1] = (short)f2bf(x[1]);
  r[2] = (short)f2bf(x[2]); r[3] = (short)f2bf(x[3]);
  r[4] = (short)f2bf(y[0]); r[5] = (short)f2bf(y[1]);
  r[6] = (short)f2bf(y[2]); r[7] = (short)f2bf(y[3]);
  return r;
}

// ---------------- prep + degree count (R7: fused; cnt pre-zeroed) -----------
__global__ void k_prep(const float* __restrict__ Ws, const float* __restrict__ Wn,
                       const float* __restrict__ Wm, const float* __restrict__ Wg,
                       const float* __restrict__ b_sage, const float* __restrict__ bg,
                       const float* __restrict__ bm, const float* __restrict__ ln_g,
                       const float* __restrict__ ln_b, const int* __restrict__ dst,
                       u16* __restrict__ WmT, u16* __restrict__ WsT, u16* __restrict__ WnT,
                       u16* __restrict__ WsgT, u16* __restrict__ WngT, u16* __restrict__ WgBT,
                       float* __restrict__ bm_f, float* __restrict__ lng_f,
                       float* __restrict__ lnb_f, float* __restrict__ bsage_f,
                       float* __restrict__ bsg, int* __restrict__ cnt, int E) {
  int idx = blockIdx.x * blockDim.x + threadIdx.x;
  int stride = gridDim.x * blockDim.x;
  for (int i = idx; i < 32768; i += stride) {
    int n = i >> 8, k = i & 255;
    WmT[n * 256 + k] = f2bf(Wm[k * 128 + n]);
  }
  for (int i = idx; i < 16384; i += stride) {
    int n = i >> 7, k = i & 127;
    WsT[i] = f2bf(Ws[k * 128 + n]);
    WnT[i] = f2bf(Wn[k * 128 + n]);
    WgBT[i] = f2bf(Wg[(128 + k) * 128 + n]);
  }
  for (int i = idx; i < 16384; i += stride) {
    int c = i >> 7, k = i & 127;
    float s1 = 0.f, s2 = 0.f;
    for (int j = 0; j < 128; ++j) {
      float wg = Wg[j * 128 + c];
      s1 += Ws[k * 128 + j] * wg;
      s2 += Wn[k * 128 + j] * wg;
    }
    WsgT[c * 128 + k] = f2bf(s1);
    WngT[c * 128 + k] = f2bf(s2);
  }
  for (int i = idx; i < 128; i += stride) {
    bm_f[i] = bm[i];
    lng_f[i] = ln_g[i];
    lnb_f[i] = ln_b[i];
    bsage_f[i] = b_sage[i];
    float s = bg[i];
    for (int j = 0; j < 128; ++j) s += b_sage[j] * Wg[j * 128 + i];
    bsg[i] = s;
  }
  for (int e = idx; e < E; e += stride) atomicAdd(&cnt[dst[e]], 1);
}

// ---------------- CSR scan: single kernel (R8 version, verified) ------------
__global__ void k_scan(const int* __restrict__ cnt, int* __restrict__ rowptr,
                       int* __restrict__ cursor, int N) {
  __shared__ int ws2[4];
  __shared__ int s[256];
  int t = threadIdx.x;
  int c = blockIdx.x;
  int lim = c * 256;
  int base = 0;
  for (int j = t; j < lim; j += 256) base += cnt[j];
#pragma unroll
  for (int m = 1; m < 64; m <<= 1) base += __shfl_xor(base, m, 64);
  if ((t & 63) == 0) ws2[t >> 6] = base;
  __syncthreads();
  base = ws2[0] + ws2[1] + ws2[2] + ws2[3];
  int i = lim + t;
  int v = (i < N) ? cnt[i] : 0;
  s[t] = v;
  __syncthreads();
  for (int off = 1; off < 256; off <<= 1) {
    int x = (t >= off) ? s[t - off] : 0;
    __syncthreads();
    s[t] += x;
    __syncthreads();
  }
  int excl = base + s[t] - v;
  if (i < N) {
    rowptr[i] = excl;
    cursor[i] = excl;
    if (i == N - 1) rowptr[N] = excl + v;
  }
}

// ---------------- fused perm + node MLP (R9) --------------------------------
// Blocks [0, PB): edge permutation scatter (needs cursor from k_scan).
// Blocks [PB, PB+GN): R3-verified node MLP persistent loop (needs only WmT).
// Independent workloads overlapped in one dispatch; perm's atomic/scatter
// latency hides under node's MFMA waves.
__global__ __launch_bounds__(512) void k_pnode(
    const int* __restrict__ src, const int* __restrict__ dst,
    int* __restrict__ cursor, int* __restrict__ src_sorted, int E, int PB,
    const float* __restrict__ h, const float* __restrict__ ctx,
    const u16* __restrict__ WmT, const float* __restrict__ bm_f,
    const float* __restrict__ lng_f, const float* __restrict__ lnb_f,
    u16* __restrict__ hm, int N) {
  int tid = threadIdx.x;
  if ((int)blockIdx.x < PB) {
    int e = blockIdx.x * 512 + tid;
    if (e < E) {
      int p = atomicAdd(&cursor[dst[e]], 1);
      src_sorted[p] = src[e];
    }
    return;
  }
  __shared__ u16 atile[16 * 256];
  __shared__ u16 mtile[16 * 128];
  __shared__ float scr[8 * 16 * 2];
  int GN = gridDim.x - PB;
  int nbid = blockIdx.x - PB;
  int lane = tid & 63;
  int wave = tid >> 6;
  int col16 = lane & 15;
  int quad = lane >> 4;

  sh8 areg[8];
#pragma unroll
  for (int ks = 0; ks < 8; ++ks)
    areg[ks] = *(const sh8*)&WmT[(size_t)(wave * 16 + col16) * 256 + ks * 32 + quad * 8];

  float bmv[4], gv[4], bv[4];
#pragma unroll
  for (int r = 0; r < 4; ++r) {
    int c = wave * 16 + quad * 4 + r;
    bmv[r] = bm_f[c]; gv[r] = lng_f[c]; bv[r] = lnb_f[c];
  }

  int srow = tid >> 5;
  int c8 = tid & 31;
  int TT = (N + 15) >> 4;
  for (int tile = nbid; tile < TT; tile += GN) {
    int n0 = tile * 16;
    {
      int node = min(n0 + srow, N - 1);
      sh8 a = (c8 < 16) ? load8f_nt(h, (size_t)node * 128 + c8 * 8)
                        : load8f_nt(ctx, (size_t)node * 128 + (c8 - 16) * 8);
      *(sh8*)&atile[srow * 256 + ((c8 ^ (srow & 7)) << 3)] = a;
      if (c8 < 16 && n0 + srow < N)
        __builtin_nontemporal_store(a, (sh8*)&hm[(size_t)(n0 + srow) * 256 + c8 * 8]);
    }
    __syncthreads();
    f32x4 acc = (f32x4)0.0f;
#pragma unroll
    for (int ks = 0; ks < 8; ++ks) {
      int chunk = ks * 4 + quad;
      sh8 b = *(const sh8*)&atile[col16 * 256 + ((chunk ^ (col16 & 7)) << 3)];
      acc = __builtin_amdgcn_mfma_f32_16x16x32_bf16(areg[ks], b, acc, 0, 0, 0);
    }
    float v[4], s1 = 0.f, s2 = 0.f;
#pragma unroll
    for (int r = 0; r < 4; ++r) {
      v[r] = acc[r] + bmv[r];
      s1 += v[r]; s2 += v[r] * v[r];
    }
    s1 += __shfl_xor(s1, 16, 64); s2 += __shfl_xor(s2, 16, 64);
    s1 += __shfl_xor(s1, 32, 64); s2 += __shfl_xor(s2, 32, 64);
    if (lane < 16) {
      scr[(wave * 16 + lane) * 2 + 0] = s1;
      scr[(wave * 16 + lane) * 2 + 1] = s2;
    }
    __syncthreads();
    float t1 = 0.f, t2 = 0.f;
#pragma unroll
    for (int w2 = 0; w2 < 8; ++w2) {
      t1 += scr[(w2 * 16 + col16) * 2 + 0];
      t2 += scr[(w2 * 16 + col16) * 2 + 1];
    }
    float mu = t1 * (1.f / 128.f);
    float var = t2 * (1.f / 128.f) - mu * mu;
    float rstd = rsqrtf(fmaxf(var, 0.f) + 1e-5f);
    us4 pk;
#pragma unroll
    for (int r = 0; r < 4; ++r) {
      float x = (v[r] - mu) * rstd * gv[r] + bv[r];
      x = x > 0.f ? x : 0.f;
      pk[r] = f2bf(x);
    }
    *(us4*)&mtile[col16 * 128 + wave * 16 + quad * 4] = pk;
    __syncthreads();
    if (tid < 256) {
      int row = tid >> 4, ch = tid & 15;
      if (n0 + row < N) {
        sh8 mv = *(const sh8*)&mtile[row * 128 + ch * 8];
        __builtin_nontemporal_store(mv, (sh8*)&hm[(size_t)(n0 + row) * 256 + 128 + ch * 8]);
      }
    }
  }
}

// ---------------- per-node aggregation over hm rows (R7 verified) -----------
__global__ __launch_bounds__(256) void k_agg(
    const u16* __restrict__ hm, const int* __restrict__ rowptr,
    const int* __restrict__ src_sorted,
    u16* __restrict__ nm, u16* __restrict__ cagg, int N) {
  int gw = (blockIdx.x * 256 + threadIdx.x) >> 6;
  int lane = threadIdx.x & 63;
  int half = lane >> 5;
  int cl = lane & 31;
  int tw = (gridDim.x * 256) >> 6;
  for (int n = gw; n < N; n += tw) {
    int b = rowptr[n], e = rowptr[n + 1];
    float a0 = 0.f, a1 = 0.f, a2 = 0.f, a3 = 0.f;
    float a4 = 0.f, a5 = 0.f, a6 = 0.f, a7 = 0.f;
    int i = b;
    for (; i + 8 <= e; i += 8) {
      int s0 = src_sorted[i + half];
      int s1 = src_sorted[i + 2 + half];
      int s2 = src_sorted[i + 4 + half];
      int s3 = src_sorted[i + 6 + half];
      sh8 v0 = *(const sh8*)(hm + (size_t)s0 * 256 + (cl << 3));
      sh8 v1 = *(const sh8*)(hm + (size_t)s1 * 256 + (cl << 3));
      sh8 v2 = *(const sh8*)(hm + (size_t)s2 * 256 + (cl << 3));
      sh8 v3 = *(const sh8*)(hm + (size_t)s3 * 256 + (cl << 3));
      a0 += bf2f((u16)v0[0]) + bf2f((u16)v1[0]) + bf2f((u16)v2[0]) + bf2f((u16)v3[0]);
      a1 += bf2f((u16)v0[1]) + bf2f((u16)v1[1]) + bf2f((u16)v2[1]) + bf2f((u16)v3[1]);
      a2 += bf2f((u16)v0[2]) + bf2f((u16)v1[2]) + bf2f((u16)v2[2]) + bf2f((u16)v3[2]);
      a3 += bf2f((u16)v0[3]) + bf2f((u16)v1[3]) + bf2f((u16)v2[3]) + bf2f((u16)v3[3]);
      a4 += bf2f((u16)v0[4]) + bf2f((u16)v1[4]) + bf2f((u16)v2[4]) + bf2f((u16)v3[4]);
      a5 += bf2f((u16)v0[5]) + bf2f((u16)v1[5]) + bf2f((u16)v2[5]) + bf2f((u16)v3[5]);
      a6 += bf2f((u16)v0[6]) + bf2f((u16)v1[6]) + bf2f((u16)v2[6]) + bf2f((u16)v3[6]);
      a7 += bf2f((u16)v0[7]) + bf2f((u16)v1[7]) + bf2f((u16)v2[7]) + bf2f((u16)v3[7]);
    }
    for (; i + 4 <= e; i += 4) {
      int s0 = src_sorted[i + half];
      int s1 = src_sorted[i + 2 + half];
      sh8 v0 = *(const sh8*)(hm + (size_t)s0 * 256 + (cl << 3));
      sh8 v1 = *(const sh8*)(hm + (size_t)s1 * 256 + (cl << 3));
      a0 += bf2f((u16)v0[0]) + bf2f((u16)v1[0]);
      a1 += bf2f((u16)v0[1]) + bf2f((u16)v1[1]);
      a2 += bf2f((u16)v0[2]) + bf2f((u16)v1[2]);
      a3 += bf2f((u16)v0[3]) + bf2f((u16)v1[3]);
      a4 += bf2f((u16)v0[4]) + bf2f((u16)v1[4]);
      a5 += bf2f((u16)v0[5]) + bf2f((u16)v1[5]);
      a6 += bf2f((u16)v0[6]) + bf2f((u16)v1[6]);
      a7 += bf2f((u16)v0[7]) + bf2f((u16)v1[7]);
    }
    for (; i + 2 <= e; i += 2) {
      int s0 = src_sorted[i + half];
      sh8 v0 = *(const sh8*)(hm + (size_t)s0 * 256 + (cl << 3));
      a0 += bf2f((u16)v0[0]); a1 += bf2f((u16)v0[1]);
      a2 += bf2f((u16)v0[2]); a3 += bf2f((u16)v0[3]);
      a4 += bf2f((u16)v0[4]); a5 += bf2f((u16)v0[5]);
      a6 += bf2f((u16)v0[6]); a7 += bf2f((u16)v0[7]);
    }
    if (i < e && half == 0) {
      int s0 = src_sorted[i];
      sh8 v0 = *(const sh8*)(hm + (size_t)s0 * 256 + (cl << 3));
      a0 += bf2f((u16)v0[0]); a1 += bf2f((u16)v0[1]);
      a2 += bf2f((u16)v0[2]); a3 += bf2f((u16)v0[3]);
      a4 += bf2f((u16)v0[4]); a5 += bf2f((u16)v0[5]);
      a6 += bf2f((u16)v0[6]); a7 += bf2f((u16)v0[7]);
    }
    a0 += __shfl_xor(a0, 32, 64); a1 += __shfl_xor(a1, 32, 64);
    a2 += __shfl_xor(a2, 32, 64); a3 += __shfl_xor(a3, 32, 64);
    a4 += __shfl_xor(a4, 32, 64); a5 += __shfl_xor(a5, 32, 64);
    a6 += __shfl_xor(a6, 32, 64); a7 += __shfl_xor(a7, 32, 64);
    if (half == 0) {
      float inv = (e > b) ? 1.f / (float)(e - b) : 0.f;
      sh8 p;
      p[0] = (short)f2bf(a0 * inv); p[1] = (short)f2bf(a1 * inv);
      p[2] = (short)f2bf(a2 * inv); p[3] = (short)f2bf(a3 * inv);
      p[4] = (short)f2bf(a4 * inv); p[5] = (short)f2bf(a5 * inv);
      p[6] = (short)f2bf(a6 * inv); p[7] = (short)f2bf(a7 * inv);
      if (cl < 16)
        *(sh8*)(nm + (size_t)n * 128 + (cl << 3)) = p;
      else
        *(sh8*)(cagg + (size_t)n * 128 + ((cl - 16) << 3)) = p;
    }
  }
}

// ---------------- fused node GEMMs + gate + blend (R7 verified) -------------
__global__ __launch_bounds__(256, 3) void k_out(
    const u16* __restrict__ hm, const u16* __restrict__ nm, const u16* __restrict__ cagg,
    const u16* __restrict__ WsT, const u16* __restrict__ WnT,
    const u16* __restrict__ WsgT, const u16* __restrict__ WngT, const u16* __restrict__ WgBT,
    const float* __restrict__ bsage_f, const float* __restrict__ bsg,
    float* __restrict__ out, int N) {
  __shared__ u16 blds[5 * 32 * 128];  // 40 KB
  int tid = threadIdx.x;
  int bid = blockIdx.x;
  int q = (bid >> 3) & 3;                       // col group, same XCD for all 4
  int tg = (bid & 7) | ((bid >> 5) << 3);       // tile-group 0..255
  {
    const u16* matp[5] = {WsT, WnT, WsgT, WngT, WgBT};
#pragma unroll
    for (int m = 0; m < 5; ++m) {
#pragma unroll
      for (int j = 0; j < 2; ++j) {
        int f = tid + j * 256;
        int lc = f >> 4, kc = f & 15;
        int kcs = kc ^ (lc & 15);
        *(sh8*)&blds[(m * 32 + lc) * 128 + kcs * 8] =
            *(const sh8*)&matp[m][(size_t)(q * 32 + lc) * 128 + kc * 8];
      }
    }
  }
  __syncthreads();
  int lane = tid & 63;
  int wave = tid >> 6;
  int col = lane & 15, quad = lane >> 4;
  float bsv[2], bgv[2];
#pragma unroll
  for (int tt = 0; tt < 2; ++tt) {
    int gc = q * 32 + tt * 16 + col;
    bsv[tt] = bsage_f[gc];
    bgv[tt] = bsg[gc];
  }
  int TT = (N + 15) >> 4;
  int slots = (gridDim.x >> 2) * 4;
  for (int tile = tg * 4 + wave; tile < TT; tile += slots) {
    int nr = min(tile * 16 + col, N - 1);
    f32x4 as[2], ag[2];
#pragma unroll
    for (int tt = 0; tt < 2; ++tt) {
      as[tt] = (f32x4)0.0f;
      ag[tt] = (f32x4)0.0f;
    }
#pragma unroll 1
    for (int ks = 0; ks < 4; ++ks) {
      int k = ks * 32 + quad * 8;
      sh8 ah = *(const sh8*)&hm[(size_t)nr * 256 + k];
      sh8 am = *(const sh8*)&nm[(size_t)nr * 128 + k];
      sh8 ac = *(const sh8*)&cagg[(size_t)nr * 128 + k];
      int kcs8 = ((ks * 4 + quad) ^ col) * 8;
#pragma unroll
      for (int tt = 0; tt < 2; ++tt) {
        int lc = tt * 16 + col;
        sh8 b1 = *(const sh8*)&blds[(0 * 32 + lc) * 128 + kcs8];
        sh8 b2 = *(const sh8*)&blds[(1 * 32 + lc) * 128 + kcs8];
        sh8 b3 = *(const sh8*)&blds[(2 * 32 + lc) * 128 + kcs8];
        sh8 b4 = *(const sh8*)&blds[(3 * 32 + lc) * 128 + kcs8];
        sh8 b5 = *(const sh8*)&blds[(4 * 32 + lc) * 128 + kcs8];
        as[tt] = __builtin_amdgcn_mfma_f32_16x16x32_bf16(ah, b1, as[tt], 0, 0, 0);
        as[tt] = __builtin_amdgcn_mfma_f32_16x16x32_bf16(am, b2, as[tt], 0, 0, 0);
        ag[tt] = __builtin_amdgcn_mfma_f32_16x16x32_bf16(ah, b3, ag[tt], 0, 0, 0);
        ag[tt] = __builtin_amdgcn_mfma_f32_16x16x32_bf16(am, b4, ag[tt], 0, 0, 0);
        ag[tt] = __builtin_amdgcn_mfma_f32_16x16x32_bf16(ac, b5, ag[tt], 0, 0, 0);
      }
    }
#pragma unroll
    for (int r = 0; r < 4; ++r) {
      int n = tile * 16 + quad * 4 + r;
      if (n < N) {
#pragma unroll
        for (int tt = 0; tt < 2; ++tt) {
          int gc = q * 32 + tt * 16 + col;
          float sv = as[tt][r] + bsv[tt];
          float gl = ag[tt][r] + bgv[tt];
          float g = 1.f / (1.f + __expf(-gl));
          float ca = bf2f(cagg[(size_t)n * 128 + gc]);
          __builtin_nontemporal_store(g * sv + (1.f - g) * ca,
                                      &out[(size_t)n * 128 + gc]);
        }
      }
    }
  }
}

extern "C" void kernel_launch(void* const* d_in, const int* in_sizes, int n_in,
                              void* d_out, int out_size, void* d_ws, size_t ws_size,
                              hipStream_t stream) {
  const float* h = (const float*)d_in[0];
  const float* ctx = (const float*)d_in[1];
  const int* src = (const int*)d_in[2];
  const int* dst = (const int*)d_in[3];
  const float* Ws = (const float*)d_in[4];
  const float* Wn = (const float*)d_in[5];
  const float* b_sage = (const float*)d_in[6];
  const float* Wm = (const float*)d_in[7];
  const float* bm = (const float*)d_in[8];
  const float* ln_g = (const float*)d_in[9];
  const float* ln_b = (const float*)d_in[10];
  const float* Wg = (const float*)d_in[11];
  const float* bg = (const float*)d_in[12];
  int N = in_sizes[0] / 128;
  int E = in_sizes[2];

  char* w = (char*)d_ws;
  auto carve = [&](size_t bytes) {
    char* p = w;
    w += (bytes + 255) & ~(size_t)255;
    return p;
  };
  int* cnt = (int*)carve((size_t)N * 4);
  int* rowptr = (int*)carve((size_t)(N + 1) * 4);
  int* cursor = (int*)carve((size_t)N * 4);
  int* src_sorted = (int*)carve((size_t)E * 4);
  int NB = (N + 255) / 256;
  u16* WmT = (u16*)carve(32768 * 2);
  u16* WsT = (u16*)carve(16384 * 2);
  u16* WnT = (u16*)carve(16384 * 2);
  u16* WsgT = (u16*)carve(16384 * 2);
  u16* WngT = (u16*)carve(16384 * 2);
  u16* WgBT = (u16*)carve(16384 * 2);
  float* bm_f = (float*)carve(128 * 4);
  float* lng_f = (float*)carve(128 * 4);
  float* lnb_f = (float*)carve(128 * 4);
  float* bsage_f = (float*)carve(128 * 4);
  float* bsg = (float*)carve(128 * 4);
  u16* hm = (u16*)carve((size_t)N * 256 * 2);
  u16* nm = (u16*)carve((size_t)N * 128 * 2);
  u16* cagg = (u16*)carve((size_t)N * 128 * 2);

  hipMemsetAsync(cnt, 0, (size_t)N * 4, stream);
  k_prep<<<256, 256, 0, stream>>>(Ws, Wn, Wm, Wg, b_sage, bg, bm, ln_g, ln_b, dst,
                                  WmT, WsT, WnT, WsgT, WngT, WgBT,
                                  bm_f, lng_f, lnb_f, bsage_f, bsg, cnt, E);
  k_scan<<<NB, 256, 0, stream>>>(cnt, rowptr, cursor, N);
  // fused perm + node: blocks [0,PB) scatter edges, [PB,PB+GN) run node MLP
  int PB = (E + 511) / 512;
  int TT = (N + 15) / 16;
  int GN = TT < 1024 ? TT : 1024;
  k_pnode<<<PB + GN, 512, 0, stream>>>(src, dst, cursor, src_sorted, E, PB,
                                       h, ctx, WmT, bm_f, lng_f, lnb_f, hm, N);
  k_agg<<<4096, 256, 0, stream>>>(hm, rowptr, src_sorted, nm, cagg, N);
  k_out<<<1024, 256, 0, stream>>>(hm, nm, cagg, WsT, WnT, WsgT, WngT, WgBT,
                                  bsage_f, bsg, (float*)d_out, N);
}

// Round 10
// 271.296 us; speedup vs baseline: 1.0699x; 1.0166x over previous
//
#include <hip/hip_runtime.h>

typedef unsigned short u16;
typedef unsigned int u32;
typedef __attribute__((ext_vector_type(8))) short sh8;
typedef __attribute__((ext_vector_type(4))) float f32x4;
typedef __attribute__((ext_vector_type(4))) unsigned short us4;

__device__ __forceinline__ float bf2f(u16 u) {
  union { u32 i; float f; } x; x.i = ((u32)u) << 16; return x.f;
}
__device__ __forceinline__ u16 f2bf(float f) {
  union { float f; u32 i; } x; x.f = f;
  u32 u = x.i;
  u32 r = (u + 0x7FFFu + ((u >> 16) & 1u)) >> 16;
  return (u16)r;
}

__device__ __forceinline__ sh8 load8f_nt(const float* p, size_t off) {
  const f32x4* f = (const f32x4*)(p + off);
  f32x4 x = __builtin_nontemporal_load(f);
  f32x4 y = __builtin_nontemporal_load(f + 1);
  sh8 r;
  r[0] = (short)f2bf(x[0]); r[1] = (short)f2bf(x[1]);
  r[2] = (short)f2bf(x[2]); r[3] = (short)f2bf(x[3]);
  r[4] = (short)f2bf(y[0]); r[5] = (short)f2bf(y[1]);
  r[6] = (short)f2bf(y[2]); r[7] = (short)f2bf(y[3]);
  return r;
}

// ---------------- prep + degree count (R7 verified; cnt pre-zeroed) ---------
__global__ void k_prep(const float* __restrict__ Ws, const float* __restrict__ Wn,
                       const float* __restrict__ Wm, const float* __restrict__ Wg,
                       const float* __restrict__ b_sage, const float* __restrict__ bg,
                       const float* __restrict__ bm, const float* __restrict__ ln_g,
                       const float* __restrict__ ln_b, const int* __restrict__ dst,
                       u16* __restrict__ WmT, u16* __restrict__ WsT, u16* __restrict__ WnT,
                       u16* __restrict__ WsgT, u16* __restrict__ WngT, u16* __restrict__ WgBT,
                       float* __restrict__ bm_f, float* __restrict__ lng_f,
                       float* __restrict__ lnb_f, float* __restrict__ bsage_f,
                       float* __restrict__ bsg, int* __restrict__ cnt, int E) {
  int idx = blockIdx.x * blockDim.x + threadIdx.x;
  int stride = gridDim.x * blockDim.x;
  for (int i = idx; i < 32768; i += stride) {
    int n = i >> 8, k = i & 255;
    WmT[n * 256 + k] = f2bf(Wm[k * 128 + n]);
  }
  for (int i = idx; i < 16384; i += stride) {
    int n = i >> 7, k = i & 127;
    WsT[i] = f2bf(Ws[k * 128 + n]);
    WnT[i] = f2bf(Wn[k * 128 + n]);
    WgBT[i] = f2bf(Wg[(128 + k) * 128 + n]);
  }
  for (int i = idx; i < 16384; i += stride) {
    int c = i >> 7, k = i & 127;
    float s1 = 0.f, s2 = 0.f;
    for (int j = 0; j < 128; ++j) {
      float wg = Wg[j * 128 + c];
      s1 += Ws[k * 128 + j] * wg;
      s2 += Wn[k * 128 + j] * wg;
    }
    WsgT[c * 128 + k] = f2bf(s1);
    WngT[c * 128 + k] = f2bf(s2);
  }
  for (int i = idx; i < 128; i += stride) {
    bm_f[i] = bm[i];
    lng_f[i] = ln_g[i];
    lnb_f[i] = ln_b[i];
    bsage_f[i] = b_sage[i];
    float s = bg[i];
    for (int j = 0; j < 128; ++j) s += b_sage[j] * Wg[j * 128 + i];
    bsg[i] = s;
  }
  for (int e = idx; e < E; e += stride) atomicAdd(&cnt[dst[e]], 1);
}

// ---------------- CSR scan: single kernel (verified R8/R9) ------------------
__global__ void k_scan(const int* __restrict__ cnt, int* __restrict__ rowptr,
                       int* __restrict__ cursor, int N) {
  __shared__ int ws2[4];
  __shared__ int s[256];
  int t = threadIdx.x;
  int c = blockIdx.x;
  int lim = c * 256;
  int base = 0;
  for (int j = t; j < lim; j += 256) base += cnt[j];
#pragma unroll
  for (int m = 1; m < 64; m <<= 1) base += __shfl_xor(base, m, 64);
  if ((t & 63) == 0) ws2[t >> 6] = base;
  __syncthreads();
  base = ws2[0] + ws2[1] + ws2[2] + ws2[3];
  int i = lim + t;
  int v = (i < N) ? cnt[i] : 0;
  s[t] = v;
  __syncthreads();
  for (int off = 1; off < 256; off <<= 1) {
    int x = (t >= off) ? s[t - off] : 0;
    __syncthreads();
    s[t] += x;
    __syncthreads();
  }
  int excl = base + s[t] - v;
  if (i < N) {
    rowptr[i] = excl;
    cursor[i] = excl;
    if (i == N - 1) rowptr[N] = excl + v;
  }
}

__global__ void k_perm(const int* __restrict__ src, const int* __restrict__ dst,
                       int* __restrict__ cursor, int* __restrict__ src_sorted, int E) {
  int e = blockIdx.x * blockDim.x + threadIdx.x;
  if (e < E) {
    int p = atomicAdd(&cursor[dst[e]], 1);
    src_sorted[p] = src[e];
  }
}

// ---------------- node MLP (R3 verified structure) --------------------------
__global__ __launch_bounds__(512) void k_node(
    const float* __restrict__ h, const float* __restrict__ ctx,
    const u16* __restrict__ WmT, const float* __restrict__ bm_f,
    const float* __restrict__ lng_f, const float* __restrict__ lnb_f,
    u16* __restrict__ hm, int N) {
  __shared__ u16 atile[16 * 256];
  __shared__ u16 mtile[16 * 128];
  __shared__ float scr[8 * 16 * 2];
  int tid = threadIdx.x;
  int lane = tid & 63;
  int wave = tid >> 6;
  int col16 = lane & 15;
  int quad = lane >> 4;

  sh8 areg[8];
#pragma unroll
  for (int ks = 0; ks < 8; ++ks)
    areg[ks] = *(const sh8*)&WmT[(size_t)(wave * 16 + col16) * 256 + ks * 32 + quad * 8];

  float bmv[4], gv[4], bv[4];
#pragma unroll
  for (int r = 0; r < 4; ++r) {
    int c = wave * 16 + quad * 4 + r;
    bmv[r] = bm_f[c]; gv[r] = lng_f[c]; bv[r] = lnb_f[c];
  }

  int srow = tid >> 5;
  int c8 = tid & 31;
  int TT = (N + 15) >> 4;
  for (int tile = blockIdx.x; tile < TT; tile += gridDim.x) {
    int n0 = tile * 16;
    {
      int node = min(n0 + srow, N - 1);
      sh8 a = (c8 < 16) ? load8f_nt(h, (size_t)node * 128 + c8 * 8)
                        : load8f_nt(ctx, (size_t)node * 128 + (c8 - 16) * 8);
      *(sh8*)&atile[srow * 256 + ((c8 ^ (srow & 7)) << 3)] = a;
      if (c8 < 16 && n0 + srow < N)
        __builtin_nontemporal_store(a, (sh8*)&hm[(size_t)(n0 + srow) * 256 + c8 * 8]);
    }
    __syncthreads();
    f32x4 acc = (f32x4)0.0f;
#pragma unroll
    for (int ks = 0; ks < 8; ++ks) {
      int chunk = ks * 4 + quad;
      sh8 b = *(const sh8*)&atile[col16 * 256 + ((chunk ^ (col16 & 7)) << 3)];
      acc = __builtin_amdgcn_mfma_f32_16x16x32_bf16(areg[ks], b, acc, 0, 0, 0);
    }
    float v[4], s1 = 0.f, s2 = 0.f;
#pragma unroll
    for (int r = 0; r < 4; ++r) {
      v[r] = acc[r] + bmv[r];
      s1 += v[r]; s2 += v[r] * v[r];
    }
    s1 += __shfl_xor(s1, 16, 64); s2 += __shfl_xor(s2, 16, 64);
    s1 += __shfl_xor(s1, 32, 64); s2 += __shfl_xor(s2, 32, 64);
    if (lane < 16) {
      scr[(wave * 16 + lane) * 2 + 0] = s1;
      scr[(wave * 16 + lane) * 2 + 1] = s2;
    }
    __syncthreads();
    float t1 = 0.f, t2 = 0.f;
#pragma unroll
    for (int w2 = 0; w2 < 8; ++w2) {
      t1 += scr[(w2 * 16 + col16) * 2 + 0];
      t2 += scr[(w2 * 16 + col16) * 2 + 1];
    }
    float mu = t1 * (1.f / 128.f);
    float var = t2 * (1.f / 128.f) - mu * mu;
    float rstd = rsqrtf(fmaxf(var, 0.f) + 1e-5f);
    us4 pk;
#pragma unroll
    for (int r = 0; r < 4; ++r) {
      float x = (v[r] - mu) * rstd * gv[r] + bv[r];
      x = x > 0.f ? x : 0.f;
      pk[r] = f2bf(x);
    }
    *(us4*)&mtile[col16 * 128 + wave * 16 + quad * 4] = pk;
    __syncthreads();
    if (tid < 256) {
      int row = tid >> 4, ch = tid & 15;
      if (n0 + row < N) {
        sh8 mv = *(const sh8*)&mtile[row * 128 + ch * 8];
        __builtin_nontemporal_store(mv, (sh8*)&hm[(size_t)(n0 + row) * 256 + 128 + ch * 8]);
      }
    }
  }
}

// ---------------- per-node aggregation (R5/R6 verified) ---------------------
__global__ __launch_bounds__(256) void k_agg(
    const u16* __restrict__ hm, const int* __restrict__ rowptr,
    const int* __restrict__ src_sorted,
    u16* __restrict__ nm, u16* __restrict__ cagg, int N) {
  int gw = (blockIdx.x * 256 + threadIdx.x) >> 6;
  int lane = threadIdx.x & 63;
  int half = lane >> 5;
  int cl = lane & 31;
  int tw = (gridDim.x * 256) >> 6;
  for (int n = gw; n < N; n += tw) {
    int b = rowptr[n], e = rowptr[n + 1];
    float a0 = 0.f, a1 = 0.f, a2 = 0.f, a3 = 0.f;
    float a4 = 0.f, a5 = 0.f, a6 = 0.f, a7 = 0.f;
    int i = b;
    for (; i + 8 <= e; i += 8) {
      int s0 = src_sorted[i + half];
      int s1 = src_sorted[i + 2 + half];
      int s2 = src_sorted[i + 4 + half];
      int s3 = src_sorted[i + 6 + half];
      sh8 v0 = *(const sh8*)(hm + (size_t)s0 * 256 + (cl << 3));
      sh8 v1 = *(const sh8*)(hm + (size_t)s1 * 256 + (cl << 3));
      sh8 v2 = *(const sh8*)(hm + (size_t)s2 * 256 + (cl << 3));
      sh8 v3 = *(const sh8*)(hm + (size_t)s3 * 256 + (cl << 3));
      a0 += bf2f((u16)v0[0]) + bf2f((u16)v1[0]) + bf2f((u16)v2[0]) + bf2f((u16)v3[0]);
      a1 += bf2f((u16)v0[1]) + bf2f((u16)v1[1]) + bf2f((u16)v2[1]) + bf2f((u16)v3[1]);
      a2 += bf2f((u16)v0[2]) + bf2f((u16)v1[2]) + bf2f((u16)v2[2]) + bf2f((u16)v3[2]);
      a3 += bf2f((u16)v0[3]) + bf2f((u16)v1[3]) + bf2f((u16)v2[3]) + bf2f((u16)v3[3]);
      a4 += bf2f((u16)v0[4]) + bf2f((u16)v1[4]) + bf2f((u16)v2[4]) + bf2f((u16)v3[4]);
      a5 += bf2f((u16)v0[5]) + bf2f((u16)v1[5]) + bf2f((u16)v2[5]) + bf2f((u16)v3[5]);
      a6 += bf2f((u16)v0[6]) + bf2f((u16)v1[6]) + bf2f((u16)v2[6]) + bf2f((u16)v3[6]);
      a7 += bf2f((u16)v0[7]) + bf2f((u16)v1[7]) + bf2f((u16)v2[7]) + bf2f((u16)v3[7]);
    }
    for (; i + 4 <= e; i += 4) {
      int s0 = src_sorted[i + half];
      int s1 = src_sorted[i + 2 + half];
      sh8 v0 = *(const sh8*)(hm + (size_t)s0 * 256 + (cl << 3));
      sh8 v1 = *(const sh8*)(hm + (size_t)s1 * 256 + (cl << 3));
      a0 += bf2f((u16)v0[0]) + bf2f((u16)v1[0]);
      a1 += bf2f((u16)v0[1]) + bf2f((u16)v1[1]);
      a2 += bf2f((u16)v0[2]) + bf2f((u16)v1[2]);
      a3 += bf2f((u16)v0[3]) + bf2f((u16)v1[3]);
      a4 += bf2f((u16)v0[4]) + bf2f((u16)v1[4]);
      a5 += bf2f((u16)v0[5]) + bf2f((u16)v1[5]);
      a6 += bf2f((u16)v0[6]) + bf2f((u16)v1[6]);
      a7 += bf2f((u16)v0[7]) + bf2f((u16)v1[7]);
    }
    for (; i + 2 <= e; i += 2) {
      int s0 = src_sorted[i + half];
      sh8 v0 = *(const sh8*)(hm + (size_t)s0 * 256 + (cl << 3));
      a0 += bf2f((u16)v0[0]); a1 += bf2f((u16)v0[1]);
      a2 += bf2f((u16)v0[2]); a3 += bf2f((u16)v0[3]);
      a4 += bf2f((u16)v0[4]); a5 += bf2f((u16)v0[5]);
      a6 += bf2f((u16)v0[6]); a7 += bf2f((u16)v0[7]);
    }
    if (i < e && half == 0) {
      int s0 = src_sorted[i];
      sh8 v0 = *(const sh8*)(hm + (size_t)s0 * 256 + (cl << 3));
      a0 += bf2f((u16)v0[0]); a1 += bf2f((u16)v0[1]);
      a2 += bf2f((u16)v0[2]); a3 += bf2f((u16)v0[3]);
      a4 += bf2f((u16)v0[4]); a5 += bf2f((u16)v0[5]);
      a6 += bf2f((u16)v0[6]); a7 += bf2f((u16)v0[7]);
    }
    a0 += __shfl_xor(a0, 32, 64); a1 += __shfl_xor(a1, 32, 64);
    a2 += __shfl_xor(a2, 32, 64); a3 += __shfl_xor(a3, 32, 64);
    a4 += __shfl_xor(a4, 32, 64); a5 += __shfl_xor(a5, 32, 64);
    a6 += __shfl_xor(a6, 32, 64); a7 += __shfl_xor(a7, 32, 64);
    if (half == 0) {
      float inv = (e > b) ? 1.f / (float)(e - b) : 0.f;
      sh8 p;
      p[0] = (short)f2bf(a0 * inv); p[1] = (short)f2bf(a1 * inv);
      p[2] = (short)f2bf(a2 * inv); p[3] = (short)f2bf(a3 * inv);
      p[4] = (short)f2bf(a4 * inv); p[5] = (short)f2bf(a5 * inv);
      p[6] = (short)f2bf(a6 * inv); p[7] = (short)f2bf(a7 * inv);
      if (cl < 16)
        *(sh8*)(nm + (size_t)n * 128 + (cl << 3)) = p;
      else
        *(sh8*)(cagg + (size_t)n * 128 + ((cl - 16) << 3)) = p;
    }
  }
}

// ---------------- fused node GEMMs + gate + blend (R7 verified) -------------
__global__ __launch_bounds__(256, 3) void k_out(
    const u16* __restrict__ hm, const u16* __restrict__ nm, const u16* __restrict__ cagg,
    const u16* __restrict__ WsT, const u16* __restrict__ WnT,
    const u16* __restrict__ WsgT, const u16* __restrict__ WngT, const u16* __restrict__ WgBT,
    const float* __restrict__ bsage_f, const float* __restrict__ bsg,
    float* __restrict__ out, int N) {
  __shared__ u16 blds[5 * 32 * 128];  // 40 KB
  int tid = threadIdx.x;
  int bid = blockIdx.x;
  int q = (bid >> 3) & 3;                       // col group, same XCD for all 4
  int tg = (bid & 7) | ((bid >> 5) << 3);       // tile-group 0..255
  {
    const u16* matp[5] = {WsT, WnT, WsgT, WngT, WgBT};
#pragma unroll
    for (int m = 0; m < 5; ++m) {
#pragma unroll
      for (int j = 0; j < 2; ++j) {
        int f = tid + j * 256;
        int lc = f >> 4, kc = f & 15;
        int kcs = kc ^ (lc & 15);
        *(sh8*)&blds[(m * 32 + lc) * 128 + kcs * 8] =
            *(const sh8*)&matp[m][(size_t)(q * 32 + lc) * 128 + kc * 8];
      }
    }
  }
  __syncthreads();
  int lane = tid & 63;
  int wave = tid >> 6;
  int col = lane & 15, quad = lane >> 4;
  float bsv[2], bgv[2];
#pragma unroll
  for (int tt = 0; tt < 2; ++tt) {
    int gc = q * 32 + tt * 16 + col;
    bsv[tt] = bsage_f[gc];
    bgv[tt] = bsg[gc];
  }
  int TT = (N + 15) >> 4;
  int slots = (gridDim.x >> 2) * 4;
  for (int tile = tg * 4 + wave; tile < TT; tile += slots) {
    int nr = min(tile * 16 + col, N - 1);
    f32x4 as[2], ag[2];
#pragma unroll
    for (int tt = 0; tt < 2; ++tt) {
      as[tt] = (f32x4)0.0f;
      ag[tt] = (f32x4)0.0f;
    }
#pragma unroll 1
    for (int ks = 0; ks < 4; ++ks) {
      int k = ks * 32 + quad * 8;
      sh8 ah = *(const sh8*)&hm[(size_t)nr * 256 + k];
      sh8 am = *(const sh8*)&nm[(size_t)nr * 128 + k];
      sh8 ac = *(const sh8*)&cagg[(size_t)nr * 128 + k];
      int kcs8 = ((ks * 4 + quad) ^ col) * 8;
#pragma unroll
      for (int tt = 0; tt < 2; ++tt) {
        int lc = tt * 16 + col;
        sh8 b1 = *(const sh8*)&blds[(0 * 32 + lc) * 128 + kcs8];
        sh8 b2 = *(const sh8*)&blds[(1 * 32 + lc) * 128 + kcs8];
        sh8 b3 = *(const sh8*)&blds[(2 * 32 + lc) * 128 + kcs8];
        sh8 b4 = *(const sh8*)&blds[(3 * 32 + lc) * 128 + kcs8];
        sh8 b5 = *(const sh8*)&blds[(4 * 32 + lc) * 128 + kcs8];
        as[tt] = __builtin_amdgcn_mfma_f32_16x16x32_bf16(ah, b1, as[tt], 0, 0, 0);
        as[tt] = __builtin_amdgcn_mfma_f32_16x16x32_bf16(am, b2, as[tt], 0, 0, 0);
        ag[tt] = __builtin_amdgcn_mfma_f32_16x16x32_bf16(ah, b3, ag[tt], 0, 0, 0);
        ag[tt] = __builtin_amdgcn_mfma_f32_16x16x32_bf16(am, b4, ag[tt], 0, 0, 0);
        ag[tt] = __builtin_amdgcn_mfma_f32_16x16x32_bf16(ac, b5, ag[tt], 0, 0, 0);
      }
    }
#pragma unroll
    for (int r = 0; r < 4; ++r) {
      int n = tile * 16 + quad * 4 + r;
      if (n < N) {
#pragma unroll
        for (int tt = 0; tt < 2; ++tt) {
          int gc = q * 32 + tt * 16 + col;
          float sv = as[tt][r] + bsv[tt];
          float gl = ag[tt][r] + bgv[tt];
          float g = 1.f / (1.f + __expf(-gl));
          float ca = bf2f(cagg[(size_t)n * 128 + gc]);
          __builtin_nontemporal_store(g * sv + (1.f - g) * ca,
                                      &out[(size_t)n * 128 + gc]);
        }
      }
    }
  }
}

extern "C" void kernel_launch(void* const* d_in, const int* in_sizes, int n_in,
                              void* d_out, int out_size, void* d_ws, size_t ws_size,
                              hipStream_t stream) {
  const float* h = (const float*)d_in[0];
  const float* ctx = (const float*)d_in[1];
  const int* src = (const int*)d_in[2];
  const int* dst = (const int*)d_in[3];
  const float* Ws = (const float*)d_in[4];
  const float* Wn = (const float*)d_in[5];
  const float* b_sage = (const float*)d_in[6];
  const float* Wm = (const float*)d_in[7];
  const float* bm = (const float*)d_in[8];
  const float* ln_g = (const float*)d_in[9];
  const float* ln_b = (const float*)d_in[10];
  const float* Wg = (const float*)d_in[11];
  const float* bg = (const float*)d_in[12];
  int N = in_sizes[0] / 128;
  int E = in_sizes[2];

  char* w = (char*)d_ws;
  auto carve = [&](size_t bytes) {
    char* p = w;
    w += (bytes + 255) & ~(size_t)255;
    return p;
  };
  int* cnt = (int*)carve((size_t)N * 4);
  int* rowptr = (int*)carve((size_t)(N + 1) * 4);
  int* cursor = (int*)carve((size_t)N * 4);
  int* src_sorted = (int*)carve((size_t)E * 4);
  int NB = (N + 255) / 256;
  u16* WmT = (u16*)carve(32768 * 2);
  u16* WsT = (u16*)carve(16384 * 2);
  u16* WnT = (u16*)carve(16384 * 2);
  u16* WsgT = (u16*)carve(16384 * 2);
  u16* WngT = (u16*)carve(16384 * 2);
  u16* WgBT = (u16*)carve(16384 * 2);
  float* bm_f = (float*)carve(128 * 4);
  float* lng_f = (float*)carve(128 * 4);
  float* lnb_f = (float*)carve(128 * 4);
  float* bsage_f = (float*)carve(128 * 4);
  float* bsg = (float*)carve(128 * 4);
  u16* hm = (u16*)carve((size_t)N * 256 * 2);
  u16* nm = (u16*)carve((size_t)N * 128 * 2);
  u16* cagg = (u16*)carve((size_t)N * 128 * 2);

  hipMemsetAsync(cnt, 0, (size_t)N * 4, stream);
  k_prep<<<256, 256, 0, stream>>>(Ws, Wn, Wm, Wg, b_sage, bg, bm, ln_g, ln_b, dst,
                                  WmT, WsT, WnT, WsgT, WngT, WgBT,
                                  bm_f, lng_f, lnb_f, bsage_f, bsg, cnt, E);
  k_scan<<<NB, 256, 0, stream>>>(cnt, rowptr, cursor, N);
  k_perm<<<(E + 255) / 256, 256, 0, stream>>>(src, dst, cursor, src_sorted, E);
  int TT = (N + 15) / 16;
  int gn = TT < 1024 ? TT : 1024;
  k_node<<<gn, 512, 0, stream>>>(h, ctx, WmT, bm_f, lng_f, lnb_f, hm, N);
  k_agg<<<4096, 256, 0, stream>>>(hm, rowptr, src_sorted, nm, cagg, N);
  k_out<<<1024, 256, 0, stream>>>(hm, nm, cagg, WsT, WnT, WsgT, WngT, WgBT,
                                  bsage_f, bsg, (float*)d_out, N);
}

// Round 11
// 250.091 us; speedup vs baseline: 1.1606x; 1.0848x over previous
//
#include <hip/hip_runtime.h>

typedef unsigned short u16;
typedef unsigned int u32;
typedef __attribute__((ext_vector_type(8))) short sh8;
typedef __attribute__((ext_vector_type(4))) float f32x4;
typedef __attribute__((ext_vector_type(4))) unsigned short us4;

__device__ __forceinline__ float bf2f(u16 u) {
  union { u32 i; float f; } x; x.i = ((u32)u) << 16; return x.f;
}
__device__ __forceinline__ u16 f2bf(float f) {
  union { float f; u32 i; } x; x.f = f;
  u32 u = x.i;
  u32 r = (u + 0x7FFFu + ((u >> 16) & 1u)) >> 16;
  return (u16)r;
}

__device__ __forceinline__ sh8 load8f_nt(const float* p, size_t off) {
  const f32x4* f = (const f32x4*)(p + off);
  f32x4 x = __builtin_nontemporal_load(f);
  f32x4 y = __builtin_nontemporal_load(f + 1);
  sh8 r;
  r[0] = (short)f2bf(x[0]); r[1] = (short)f2bf(x[1]);
  r[2] = (short)f2bf(x[2]); r[3] = (short)f2bf(x[3]);
  r[4] = (short)f2bf(y[0]); r[5] = (short)f2bf(y[1]);
  r[6] = (short)f2bf(y[2]); r[7] = (short)f2bf(y[3]);
  return r;
}

// ---------------- prep + degree count (R7 verified; cnt pre-zeroed) ---------
__global__ void k_prep(const float* __restrict__ Ws, const float* __restrict__ Wn,
                       const float* __restrict__ Wm, const float* __restrict__ Wg,
                       const float* __restrict__ b_sage, const float* __restrict__ bg,
                       const float* __restrict__ bm, const float* __restrict__ ln_g,
                       const float* __restrict__ ln_b, const int* __restrict__ dst,
                       u16* __restrict__ WmT, u16* __restrict__ WsT, u16* __restrict__ WnT,
                       u16* __restrict__ WsgT, u16* __restrict__ WngT, u16* __restrict__ WgBT,
                       float* __restrict__ bm_f, float* __restrict__ lng_f,
                       float* __restrict__ lnb_f, float* __restrict__ bsage_f,
                       float* __restrict__ bsg, int* __restrict__ cnt, int E) {
  int idx = blockIdx.x * blockDim.x + threadIdx.x;
  int stride = gridDim.x * blockDim.x;
  for (int i = idx; i < 32768; i += stride) {
    int n = i >> 8, k = i & 255;
    WmT[n * 256 + k] = f2bf(Wm[k * 128 + n]);
  }
  for (int i = idx; i < 16384; i += stride) {
    int n = i >> 7, k = i & 127;
    WsT[i] = f2bf(Ws[k * 128 + n]);
    WnT[i] = f2bf(Wn[k * 128 + n]);
    WgBT[i] = f2bf(Wg[(128 + k) * 128 + n]);
  }
  for (int i = idx; i < 16384; i += stride) {
    int c = i >> 7, k = i & 127;
    float s1 = 0.f, s2 = 0.f;
    for (int j = 0; j < 128; ++j) {
      float wg = Wg[j * 128 + c];
      s1 += Ws[k * 128 + j] * wg;
      s2 += Wn[k * 128 + j] * wg;
    }
    WsgT[c * 128 + k] = f2bf(s1);
    WngT[c * 128 + k] = f2bf(s2);
  }
  for (int i = idx; i < 128; i += stride) {
    bm_f[i] = bm[i];
    lng_f[i] = ln_g[i];
    lnb_f[i] = ln_b[i];
    bsage_f[i] = b_sage[i];
    float s = bg[i];
    for (int j = 0; j < 128; ++j) s += b_sage[j] * Wg[j * 128 + i];
    bsg[i] = s;
  }
  for (int e = idx; e < E; e += stride) atomicAdd(&cnt[dst[e]], 1);
}

// ---------------- CSR scan: SPLIT 2-kernel version (R7 verified) ------------
// R10 lesson: merging these made block c re-read cnt[0..c*256) -> quadratic,
// last block's 50K-int serial sum = +17us critical path. Split is O(N).
__global__ void k_scan1(const int* __restrict__ cnt, int* __restrict__ bsum, int N) {
  int i = blockIdx.x * 256 + threadIdx.x;
  int v = (i < N) ? cnt[i] : 0;
#pragma unroll
  for (int m = 1; m < 64; m <<= 1) v += __shfl_xor(v, m, 64);
  __shared__ int ws[4];
  if ((threadIdx.x & 63) == 0) ws[threadIdx.x >> 6] = v;
  __syncthreads();
  if (threadIdx.x == 0) bsum[blockIdx.x] = ws[0] + ws[1] + ws[2] + ws[3];
}

__global__ void k_scan23(const int* __restrict__ cnt, const int* __restrict__ bsum,
                         int* __restrict__ rowptr, int* __restrict__ cursor, int N) {
  __shared__ int ws2[4];
  __shared__ int s[256];
  int t = threadIdx.x;
  int c = blockIdx.x;
  int base = 0;
  for (int j = t; j < c; j += 256) base += bsum[j];
#pragma unroll
  for (int m = 1; m < 64; m <<= 1) base += __shfl_xor(base, m, 64);
  if ((t & 63) == 0) ws2[t >> 6] = base;
  __syncthreads();
  base = ws2[0] + ws2[1] + ws2[2] + ws2[3];
  int i = c * 256 + t;
  int v = (i < N) ? cnt[i] : 0;
  s[t] = v;
  __syncthreads();
  for (int off = 1; off < 256; off <<= 1) {
    int x = (t >= off) ? s[t - off] : 0;
    __syncthreads();
    s[t] += x;
    __syncthreads();
  }
  int excl = base + s[t] - v;
  if (i < N) {
    rowptr[i] = excl;
    cursor[i] = excl;
    if (i == N - 1) rowptr[N] = excl + v;
  }
}

__global__ void k_perm(const int* __restrict__ src, const int* __restrict__ dst,
                       int* __restrict__ cursor, int* __restrict__ src_sorted, int E) {
  int e = blockIdx.x * blockDim.x + threadIdx.x;
  if (e < E) {
    int p = atomicAdd(&cursor[dst[e]], 1);
    src_sorted[p] = src[e];
  }
}

// ---------------- node MLP (R3 verified structure) --------------------------
__global__ __launch_bounds__(512) void k_node(
    const float* __restrict__ h, const float* __restrict__ ctx,
    const u16* __restrict__ WmT, const float* __restrict__ bm_f,
    const float* __restrict__ lng_f, const float* __restrict__ lnb_f,
    u16* __restrict__ hm, int N) {
  __shared__ u16 atile[16 * 256];
  __shared__ u16 mtile[16 * 128];
  __shared__ float scr[8 * 16 * 2];
  int tid = threadIdx.x;
  int lane = tid & 63;
  int wave = tid >> 6;
  int col16 = lane & 15;
  int quad = lane >> 4;

  sh8 areg[8];
#pragma unroll
  for (int ks = 0; ks < 8; ++ks)
    areg[ks] = *(const sh8*)&WmT[(size_t)(wave * 16 + col16) * 256 + ks * 32 + quad * 8];

  float bmv[4], gv[4], bv[4];
#pragma unroll
  for (int r = 0; r < 4; ++r) {
    int c = wave * 16 + quad * 4 + r;
    bmv[r] = bm_f[c]; gv[r] = lng_f[c]; bv[r] = lnb_f[c];
  }

  int srow = tid >> 5;
  int c8 = tid & 31;
  int TT = (N + 15) >> 4;
  for (int tile = blockIdx.x; tile < TT; tile += gridDim.x) {
    int n0 = tile * 16;
    {
      int node = min(n0 + srow, N - 1);
      sh8 a = (c8 < 16) ? load8f_nt(h, (size_t)node * 128 + c8 * 8)
                        : load8f_nt(ctx, (size_t)node * 128 + (c8 - 16) * 8);
      *(sh8*)&atile[srow * 256 + ((c8 ^ (srow & 7)) << 3)] = a;
      if (c8 < 16 && n0 + srow < N)
        __builtin_nontemporal_store(a, (sh8*)&hm[(size_t)(n0 + srow) * 256 + c8 * 8]);
    }
    __syncthreads();
    f32x4 acc = (f32x4)0.0f;
#pragma unroll
    for (int ks = 0; ks < 8; ++ks) {
      int chunk = ks * 4 + quad;
      sh8 b = *(const sh8*)&atile[col16 * 256 + ((chunk ^ (col16 & 7)) << 3)];
      acc = __builtin_amdgcn_mfma_f32_16x16x32_bf16(areg[ks], b, acc, 0, 0, 0);
    }
    float v[4], s1 = 0.f, s2 = 0.f;
#pragma unroll
    for (int r = 0; r < 4; ++r) {
      v[r] = acc[r] + bmv[r];
      s1 += v[r]; s2 += v[r] * v[r];
    }
    s1 += __shfl_xor(s1, 16, 64); s2 += __shfl_xor(s2, 16, 64);
    s1 += __shfl_xor(s1, 32, 64); s2 += __shfl_xor(s2, 32, 64);
    if (lane < 16) {
      scr[(wave * 16 + lane) * 2 + 0] = s1;
      scr[(wave * 16 + lane) * 2 + 1] = s2;
    }
    __syncthreads();
    float t1 = 0.f, t2 = 0.f;
#pragma unroll
    for (int w2 = 0; w2 < 8; ++w2) {
      t1 += scr[(w2 * 16 + col16) * 2 + 0];
      t2 += scr[(w2 * 16 + col16) * 2 + 1];
    }
    float mu = t1 * (1.f / 128.f);
    float var = t2 * (1.f / 128.f) - mu * mu;
    float rstd = rsqrtf(fmaxf(var, 0.f) + 1e-5f);
    us4 pk;
#pragma unroll
    for (int r = 0; r < 4; ++r) {
      float x = (v[r] - mu) * rstd * gv[r] + bv[r];
      x = x > 0.f ? x : 0.f;
      pk[r] = f2bf(x);
    }
    *(us4*)&mtile[col16 * 128 + wave * 16 + quad * 4] = pk;
    __syncthreads();
    if (tid < 256) {
      int row = tid >> 4, ch = tid & 15;
      if (n0 + row < N) {
        sh8 mv = *(const sh8*)&mtile[row * 128 + ch * 8];
        __builtin_nontemporal_store(mv, (sh8*)&hm[(size_t)(n0 + row) * 256 + 128 + ch * 8]);
      }
    }
  }
}

// ---------------- per-node aggregation (R5/R6 verified) ---------------------
__global__ __launch_bounds__(256) void k_agg(
    const u16* __restrict__ hm, const int* __restrict__ rowptr,
    const int* __restrict__ src_sorted,
    u16* __restrict__ nm, u16* __restrict__ cagg, int N) {
  int gw = (blockIdx.x * 256 + threadIdx.x) >> 6;
  int lane = threadIdx.x & 63;
  int half = lane >> 5;
  int cl = lane & 31;
  int tw = (gridDim.x * 256) >> 6;
  for (int n = gw; n < N; n += tw) {
    int b = rowptr[n], e = rowptr[n + 1];
    float a0 = 0.f, a1 = 0.f, a2 = 0.f, a3 = 0.f;
    float a4 = 0.f, a5 = 0.f, a6 = 0.f, a7 = 0.f;
    int i = b;
    for (; i + 8 <= e; i += 8) {
      int s0 = src_sorted[i + half];
      int s1 = src_sorted[i + 2 + half];
      int s2 = src_sorted[i + 4 + half];
      int s3 = src_sorted[i + 6 + half];
      sh8 v0 = *(const sh8*)(hm + (size_t)s0 * 256 + (cl << 3));
      sh8 v1 = *(const sh8*)(hm + (size_t)s1 * 256 + (cl << 3));
      sh8 v2 = *(const sh8*)(hm + (size_t)s2 * 256 + (cl << 3));
      sh8 v3 = *(const sh8*)(hm + (size_t)s3 * 256 + (cl << 3));
      a0 += bf2f((u16)v0[0]) + bf2f((u16)v1[0]) + bf2f((u16)v2[0]) + bf2f((u16)v3[0]);
      a1 += bf2f((u16)v0[1]) + bf2f((u16)v1[1]) + bf2f((u16)v2[1]) + bf2f((u16)v3[1]);
      a2 += bf2f((u16)v0[2]) + bf2f((u16)v1[2]) + bf2f((u16)v2[2]) + bf2f((u16)v3[2]);
      a3 += bf2f((u16)v0[3]) + bf2f((u16)v1[3]) + bf2f((u16)v2[3]) + bf2f((u16)v3[3]);
      a4 += bf2f((u16)v0[4]) + bf2f((u16)v1[4]) + bf2f((u16)v2[4]) + bf2f((u16)v3[4]);
      a5 += bf2f((u16)v0[5]) + bf2f((u16)v1[5]) + bf2f((u16)v2[5]) + bf2f((u16)v3[5]);
      a6 += bf2f((u16)v0[6]) + bf2f((u16)v1[6]) + bf2f((u16)v2[6]) + bf2f((u16)v3[6]);
      a7 += bf2f((u16)v0[7]) + bf2f((u16)v1[7]) + bf2f((u16)v2[7]) + bf2f((u16)v3[7]);
    }
    for (; i + 4 <= e; i += 4) {
      int s0 = src_sorted[i + half];
      int s1 = src_sorted[i + 2 + half];
      sh8 v0 = *(const sh8*)(hm + (size_t)s0 * 256 + (cl << 3));
      sh8 v1 = *(const sh8*)(hm + (size_t)s1 * 256 + (cl << 3));
      a0 += bf2f((u16)v0[0]) + bf2f((u16)v1[0]);
      a1 += bf2f((u16)v0[1]) + bf2f((u16)v1[1]);
      a2 += bf2f((u16)v0[2]) + bf2f((u16)v1[2]);
      a3 += bf2f((u16)v0[3]) + bf2f((u16)v1[3]);
      a4 += bf2f((u16)v0[4]) + bf2f((u16)v1[4]);
      a5 += bf2f((u16)v0[5]) + bf2f((u16)v1[5]);
      a6 += bf2f((u16)v0[6]) + bf2f((u16)v1[6]);
      a7 += bf2f((u16)v0[7]) + bf2f((u16)v1[7]);
    }
    for (; i + 2 <= e; i += 2) {
      int s0 = src_sorted[i + half];
      sh8 v0 = *(const sh8*)(hm + (size_t)s0 * 256 + (cl << 3));
      a0 += bf2f((u16)v0[0]); a1 += bf2f((u16)v0[1]);
      a2 += bf2f((u16)v0[2]); a3 += bf2f((u16)v0[3]);
      a4 += bf2f((u16)v0[4]); a5 += bf2f((u16)v0[5]);
      a6 += bf2f((u16)v0[6]); a7 += bf2f((u16)v0[7]);
    }
    if (i < e && half == 0) {
      int s0 = src_sorted[i];
      sh8 v0 = *(const sh8*)(hm + (size_t)s0 * 256 + (cl << 3));
      a0 += bf2f((u16)v0[0]); a1 += bf2f((u16)v0[1]);
      a2 += bf2f((u16)v0[2]); a3 += bf2f((u16)v0[3]);
      a4 += bf2f((u16)v0[4]); a5 += bf2f((u16)v0[5]);
      a6 += bf2f((u16)v0[6]); a7 += bf2f((u16)v0[7]);
    }
    a0 += __shfl_xor(a0, 32, 64); a1 += __shfl_xor(a1, 32, 64);
    a2 += __shfl_xor(a2, 32, 64); a3 += __shfl_xor(a3, 32, 64);
    a4 += __shfl_xor(a4, 32, 64); a5 += __shfl_xor(a5, 32, 64);
    a6 += __shfl_xor(a6, 32, 64); a7 += __shfl_xor(a7, 32, 64);
    if (half == 0) {
      float inv = (e > b) ? 1.f / (float)(e - b) : 0.f;
      sh8 p;
      p[0] = (short)f2bf(a0 * inv); p[1] = (short)f2bf(a1 * inv);
      p[2] = (short)f2bf(a2 * inv); p[3] = (short)f2bf(a3 * inv);
      p[4] = (short)f2bf(a4 * inv); p[5] = (short)f2bf(a5 * inv);
      p[6] = (short)f2bf(a6 * inv); p[7] = (short)f2bf(a7 * inv);
      if (cl < 16)
        *(sh8*)(nm + (size_t)n * 128 + (cl << 3)) = p;
      else
        *(sh8*)(cagg + (size_t)n * 128 + ((cl - 16) << 3)) = p;
    }
  }
}

// ---------------- fused node GEMMs + gate + blend (R7 verified) -------------
__global__ __launch_bounds__(256, 3) void k_out(
    const u16* __restrict__ hm, const u16* __restrict__ nm, const u16* __restrict__ cagg,
    const u16* __restrict__ WsT, const u16* __restrict__ WnT,
    const u16* __restrict__ WsgT, const u16* __restrict__ WngT, const u16* __restrict__ WgBT,
    const float* __restrict__ bsage_f, const float* __restrict__ bsg,
    float* __restrict__ out, int N) {
  __shared__ u16 blds[5 * 32 * 128];  // 40 KB
  int tid = threadIdx.x;
  int bid = blockIdx.x;
  int q = (bid >> 3) & 3;                       // col group, same XCD for all 4
  int tg = (bid & 7) | ((bid >> 5) << 3);       // tile-group 0..255
  {
    const u16* matp[5] = {WsT, WnT, WsgT, WngT, WgBT};
#pragma unroll
    for (int m = 0; m < 5; ++m) {
#pragma unroll
      for (int j = 0; j < 2; ++j) {
        int f = tid + j * 256;
        int lc = f >> 4, kc = f & 15;
        int kcs = kc ^ (lc & 15);
        *(sh8*)&blds[(m * 32 + lc) * 128 + kcs * 8] =
            *(const sh8*)&matp[m][(size_t)(q * 32 + lc) * 128 + kc * 8];
      }
    }
  }
  __syncthreads();
  int lane = tid & 63;
  int wave = tid >> 6;
  int col = lane & 15, quad = lane >> 4;
  float bsv[2], bgv[2];
#pragma unroll
  for (int tt = 0; tt < 2; ++tt) {
    int gc = q * 32 + tt * 16 + col;
    bsv[tt] = bsage_f[gc];
    bgv[tt] = bsg[gc];
  }
  int TT = (N + 15) >> 4;
  int slots = (gridDim.x >> 2) * 4;
  for (int tile = tg * 4 + wave; tile < TT; tile += slots) {
    int nr = min(tile * 16 + col, N - 1);
    f32x4 as[2], ag[2];
#pragma unroll
    for (int tt = 0; tt < 2; ++tt) {
      as[tt] = (f32x4)0.0f;
      ag[tt] = (f32x4)0.0f;
    }
#pragma unroll 1
    for (int ks = 0; ks < 4; ++ks) {
      int k = ks * 32 + quad * 8;
      sh8 ah = *(const sh8*)&hm[(size_t)nr * 256 + k];
      sh8 am = *(const sh8*)&nm[(size_t)nr * 128 + k];
      sh8 ac = *(const sh8*)&cagg[(size_t)nr * 128 + k];
      int kcs8 = ((ks * 4 + quad) ^ col) * 8;
#pragma unroll
      for (int tt = 0; tt < 2; ++tt) {
        int lc = tt * 16 + col;
        sh8 b1 = *(const sh8*)&blds[(0 * 32 + lc) * 128 + kcs8];
        sh8 b2 = *(const sh8*)&blds[(1 * 32 + lc) * 128 + kcs8];
        sh8 b3 = *(const sh8*)&blds[(2 * 32 + lc) * 128 + kcs8];
        sh8 b4 = *(const sh8*)&blds[(3 * 32 + lc) * 128 + kcs8];
        sh8 b5 = *(const sh8*)&blds[(4 * 32 + lc) * 128 + kcs8];
        as[tt] = __builtin_amdgcn_mfma_f32_16x16x32_bf16(ah, b1, as[tt], 0, 0, 0);
        as[tt] = __builtin_amdgcn_mfma_f32_16x16x32_bf16(am, b2, as[tt], 0, 0, 0);
        ag[tt] = __builtin_amdgcn_mfma_f32_16x16x32_bf16(ah, b3, ag[tt], 0, 0, 0);
        ag[tt] = __builtin_amdgcn_mfma_f32_16x16x32_bf16(am, b4, ag[tt], 0, 0, 0);
        ag[tt] = __builtin_amdgcn_mfma_f32_16x16x32_bf16(ac, b5, ag[tt], 0, 0, 0);
      }
    }
#pragma unroll
    for (int r = 0; r < 4; ++r) {
      int n = tile * 16 + quad * 4 + r;
      if (n < N) {
#pragma unroll
        for (int tt = 0; tt < 2; ++tt) {
          int gc = q * 32 + tt * 16 + col;
          float sv = as[tt][r] + bsv[tt];
          float gl = ag[tt][r] + bgv[tt];
          float g = 1.f / (1.f + __expf(-gl));
          float ca = bf2f(cagg[(size_t)n * 128 + gc]);
          __builtin_nontemporal_store(g * sv + (1.f - g) * ca,
                                      &out[(size_t)n * 128 + gc]);
        }
      }
    }
  }
}

extern "C" void kernel_launch(void* const* d_in, const int* in_sizes, int n_in,
                              void* d_out, int out_size, void* d_ws, size_t ws_size,
                              hipStream_t stream) {
  const float* h = (const float*)d_in[0];
  const float* ctx = (const float*)d_in[1];
  const int* src = (const int*)d_in[2];
  const int* dst = (const int*)d_in[3];
  const float* Ws = (const float*)d_in[4];
  const float* Wn = (const float*)d_in[5];
  const float* b_sage = (const float*)d_in[6];
  const float* Wm = (const float*)d_in[7];
  const float* bm = (const float*)d_in[8];
  const float* ln_g = (const float*)d_in[9];
  const float* ln_b = (const float*)d_in[10];
  const float* Wg = (const float*)d_in[11];
  const float* bg = (const float*)d_in[12];
  int N = in_sizes[0] / 128;
  int E = in_sizes[2];

  char* w = (char*)d_ws;
  auto carve = [&](size_t bytes) {
    char* p = w;
    w += (bytes + 255) & ~(size_t)255;
    return p;
  };
  int* cnt = (int*)carve((size_t)N * 4);
  int* rowptr = (int*)carve((size_t)(N + 1) * 4);
  int* cursor = (int*)carve((size_t)N * 4);
  int* src_sorted = (int*)carve((size_t)E * 4);
  int NB = (N + 255) / 256;
  int* bsum = (int*)carve((size_t)NB * 4);
  u16* WmT = (u16*)carve(32768 * 2);
  u16* WsT = (u16*)carve(16384 * 2);
  u16* WnT = (u16*)carve(16384 * 2);
  u16* WsgT = (u16*)carve(16384 * 2);
  u16* WngT = (u16*)carve(16384 * 2);
  u16* WgBT = (u16*)carve(16384 * 2);
  float* bm_f = (float*)carve(128 * 4);
  float* lng_f = (float*)carve(128 * 4);
  float* lnb_f = (float*)carve(128 * 4);
  float* bsage_f = (float*)carve(128 * 4);
  float* bsg = (float*)carve(128 * 4);
  u16* hm = (u16*)carve((size_t)N * 256 * 2);
  u16* nm = (u16*)carve((size_t)N * 128 * 2);
  u16* cagg = (u16*)carve((size_t)N * 128 * 2);

  hipMemsetAsync(cnt, 0, (size_t)N * 4, stream);
  k_prep<<<256, 256, 0, stream>>>(Ws, Wn, Wm, Wg, b_sage, bg, bm, ln_g, ln_b, dst,
                                  WmT, WsT, WnT, WsgT, WngT, WgBT,
                                  bm_f, lng_f, lnb_f, bsage_f, bsg, cnt, E);
  k_scan1<<<NB, 256, 0, stream>>>(cnt, bsum, N);
  k_scan23<<<NB, 256, 0, stream>>>(cnt, bsum, rowptr, cursor, N);
  k_perm<<<(E + 255) / 256, 256, 0, stream>>>(src, dst, cursor, src_sorted, E);
  int TT = (N + 15) / 16;
  int gn = TT < 1024 ? TT : 1024;
  k_node<<<gn, 512, 0, stream>>>(h, ctx, WmT, bm_f, lng_f, lnb_f, hm, N);
  k_agg<<<4096, 256, 0, stream>>>(hm, rowptr, src_sorted, nm, cagg, N);
  k_out<<<1024, 256, 0, stream>>>(hm, nm, cagg, WsT, WnT, WsgT, WngT, WgBT,
                                  bsage_f, bsg, (float*)d_out, N);
}